// Round 9
// baseline (698.113 us; speedup 1.0000x reference)
//
#include <hip/hip_runtime.h>
#include <stdint.h>

#define D_    1024
#define H_    4096
#define RH_   2048
#define E_    8
#define N_    4096
#define NK_   8192          // N * TOP_K
#define MT_MAX 71           // worst-case sum of ceil(cnt_e/128)
#define MT256_MAX 39        // worst-case sum of ceil(cnt_e/256)
#define DELTA_MARGIN 1e-4f  // rank2-rank3 logit margin for fp64 fixup
#define FIX_CAP 256         // max tokens handled by fixup (cnt is ~O(1) in practice)
#define PSTRIDE ((long)(NK_ + 256) * D_)   // split-K partial slab stride (f32 elems)

typedef __bf16 bf16x8 __attribute__((ext_vector_type(8)));
typedef float  f32x4  __attribute__((ext_vector_type(4)));

// ctl layout (ints): [0..7]=cnt  [8..16]=off(prefix, off[8]=8192)
// [17..25]=tile_off128 [26..33]=cursor [34]=mcount [36..44]=tile_off256

__device__ __forceinline__ unsigned short f2bf(float f) {
  union { float f; unsigned u; } v; v.f = f;
  unsigned r = v.u + 0x7fffu + ((v.u >> 16) & 1u);  // RNE
  return (unsigned short)(r >> 16);
}
__device__ __forceinline__ float bf2f(unsigned short h) {
  union { unsigned u; float f; } v; v.u = ((unsigned)h) << 16;
  return v.f;
}

// async global->LDS, 16B per lane, LDS dest must be wave-uniform base (+lane*16 implicit)
#define GLOAD16(gp, lp) \
  __builtin_amdgcn_global_load_lds((__attribute__((address_space(1))) void*)(void*)(gp), \
                                   (__attribute__((address_space(3))) void*)(lp), 16, 0, 0)

// ---------------- transpose + fp32->bf16 (optionally hi/lo split) ----------------
__global__ __launch_bounds__(256) void k_transpose(const float* __restrict__ in,
                                                   unsigned short* __restrict__ outH,
                                                   unsigned short* __restrict__ outL,
                                                   int R, int C) {
  __shared__ float t[64][65];
  const int b = blockIdx.z;
  const int c0 = blockIdx.x * 64, r0 = blockIdx.y * 64;
  const int lx = threadIdx.x & 63, ly = threadIdx.x >> 6;   // ly in 0..3
  const long inB = (long)R * C;
  const float* ip = in + b * inB + (long)r0 * C + c0 + lx;
  #pragma unroll
  for (int i = 0; i < 16; i++)
    t[ly + i * 4][lx] = ip[(long)(ly + i * 4) * C];
  __syncthreads();
  const int wy = threadIdx.x >> 2;          // column 0..63
  const int wx = (threadIdx.x & 3) * 16;    // row-chunk offset
  const int c = c0 + wy;
  const long ob = b * inB + (long)c * R + r0 + wx;
  unsigned short h[16];
  #pragma unroll
  for (int j = 0; j < 16; j++) h[j] = f2bf(t[wx + j][wy]);
  #pragma unroll
  for (int j = 0; j < 4; j++)
    *(ushort4*)&outH[ob + j * 4] = make_ushort4(h[j*4], h[j*4+1], h[j*4+2], h[j*4+3]);
  if (outL) {
    unsigned short l[16];
    #pragma unroll
    for (int j = 0; j < 16; j++) l[j] = f2bf(t[wx + j][wy] - bf2f(h[j]));
    #pragma unroll
    for (int j = 0; j < 4; j++)
      *(ushort4*)&outL[ob + j * 4] = make_ushort4(l[j*4], l[j*4+1], l[j*4+2], l[j*4+3]);
  }
}

// ---------------- LayerNorm -> xn hi/lo bf16 ----------------
__global__ __launch_bounds__(256) void k_layernorm(const float* __restrict__ x,
                                                   const float* __restrict__ g,
                                                   const float* __restrict__ b,
                                                   unsigned short* __restrict__ xnh,
                                                   unsigned short* __restrict__ xnl) {
  __shared__ float red[4];
  const int n = blockIdx.x, tid = threadIdx.x;
  float4 v = ((const float4*)(x + (long)n * D_))[tid];
  float s = v.x + v.y + v.z + v.w;
  #pragma unroll
  for (int o = 32; o >= 1; o >>= 1) s += __shfl_xor(s, o, 64);
  if ((tid & 63) == 0) red[tid >> 6] = s;
  __syncthreads();
  float mean = (red[0] + red[1] + red[2] + red[3]) * (1.f / D_);
  __syncthreads();
  float d0 = v.x - mean, d1 = v.y - mean, d2 = v.z - mean, d3 = v.w - mean;
  float ss = d0 * d0 + d1 * d1 + d2 * d2 + d3 * d3;
  #pragma unroll
  for (int o = 32; o >= 1; o >>= 1) ss += __shfl_xor(ss, o, 64);
  if ((tid & 63) == 0) red[tid >> 6] = ss;
  __syncthreads();
  float rstd = rsqrtf((red[0] + red[1] + red[2] + red[3]) * (1.f / D_) + 1e-5f);
  float4 gg = ((const float4*)g)[tid];
  float4 bb = ((const float4*)b)[tid];
  float xn0 = d0 * rstd * gg.x + bb.x;
  float xn1 = d1 * rstd * gg.y + bb.y;
  float xn2 = d2 * rstd * gg.z + bb.z;
  float xn3 = d3 * rstd * gg.w + bb.w;
  unsigned short h0 = f2bf(xn0), h1 = f2bf(xn1), h2 = f2bf(xn2), h3 = f2bf(xn3);
  ((ushort4*)xnh)[(long)n * 256 + tid] = make_ushort4(h0, h1, h2, h3);
  ((ushort4*)xnl)[(long)n * 256 + tid] = make_ushort4(
      f2bf(xn0 - bf2f(h0)), f2bf(xn1 - bf2f(h1)),
      f2bf(xn2 - bf2f(h2)), f2bf(xn3 - bf2f(h3)));
}

__global__ void k_init(int* ctl) { if (threadIdx.x < 46) ctl[threadIdx.x] = 0; }

// ---------------- router GEMM: h_r = relu(xn @ rw1 + rb1), bf16x2 -> fp32-grade ----------------
__global__ __launch_bounds__(256) void k_router_gemm(const unsigned short* __restrict__ xh,
                                                     const unsigned short* __restrict__ xl,
                                                     const unsigned short* __restrict__ bhT,  // [RH][D]
                                                     const unsigned short* __restrict__ blT,
                                                     const float* __restrict__ rb1,
                                                     float* __restrict__ h_r) {
  __shared__ __align__(16) unsigned short Ah[128 * 32], Al[128 * 32], Bh[128 * 32], Bl[128 * 32];
  const int tid = threadIdx.x, lane = tid & 63, wid = tid >> 6;
  const int m0 = blockIdx.x * 128, n0 = blockIdx.y * 128;
  const int wm = wid >> 1, wn = wid & 1;
  const int seg0 = wid * 2;
  const int srow = lane >> 2;
  const int scol = (lane & 3) * 8;
  const long a0 = (long)(m0 + seg0 * 16 + srow) * D_ + scol;
  const long a1 = a0 + 16 * D_;
  const long b0 = (long)(n0 + seg0 * 16 + srow) * D_ + scol;
  const long b1 = b0 + 16 * D_;
  const int rl = lane & 15, kh8 = (lane >> 4) * 8;
  f32x4 acc[4][4];
  #pragma unroll
  for (int i = 0; i < 4; i++)
    #pragma unroll
    for (int j = 0; j < 4; j++) acc[i][j] = 0.f;

  for (int k0 = 0; k0 < D_; k0 += 32) {
    GLOAD16(xh + a0 + k0, Ah + seg0 * 512);
    GLOAD16(xh + a1 + k0, Ah + seg0 * 512 + 512);
    GLOAD16(xl + a0 + k0, Al + seg0 * 512);
    GLOAD16(xl + a1 + k0, Al + seg0 * 512 + 512);
    GLOAD16(bhT + b0 + k0, Bh + seg0 * 512);
    GLOAD16(bhT + b1 + k0, Bh + seg0 * 512 + 512);
    GLOAD16(blT + b0 + k0, Bl + seg0 * 512);
    GLOAD16(blT + b1 + k0, Bl + seg0 * 512 + 512);
    __syncthreads();
    bf16x8 bhf[4], blf[4];
    #pragma unroll
    for (int ni = 0; ni < 4; ni++) {
      int r = (wn * 64 + ni * 16 + rl) * 32 + kh8;
      bhf[ni] = *(const bf16x8*)(Bh + r);
      blf[ni] = *(const bf16x8*)(Bl + r);
    }
    #pragma unroll
    for (int mi = 0; mi < 4; mi++) {
      int r = (wm * 64 + mi * 16 + rl) * 32 + kh8;
      bf16x8 ah = *(const bf16x8*)(Ah + r);
      bf16x8 al = *(const bf16x8*)(Al + r);
      #pragma unroll
      for (int ni = 0; ni < 4; ni++) {
        acc[mi][ni] = __builtin_amdgcn_mfma_f32_16x16x32_bf16(ah, bhf[ni], acc[mi][ni], 0, 0, 0);
        acc[mi][ni] = __builtin_amdgcn_mfma_f32_16x16x32_bf16(ah, blf[ni], acc[mi][ni], 0, 0, 0);
        acc[mi][ni] = __builtin_amdgcn_mfma_f32_16x16x32_bf16(al, bhf[ni], acc[mi][ni], 0, 0, 0);
      }
    }
    __syncthreads();
  }
  const int rg4 = (lane >> 4) * 4;
  #pragma unroll
  for (int ni = 0; ni < 4; ni++) {
    int col = n0 + wn * 64 + ni * 16 + rl;
    float bias = rb1[col];
    #pragma unroll
    for (int mi = 0; mi < 4; mi++) {
      int row = m0 + wm * 64 + mi * 16 + rg4;
      #pragma unroll
      for (int r = 0; r < 4; r++) {
        float v = acc[mi][ni][r] + bias;
        h_r[(long)(row + r) * RH_ + col] = v > 0.f ? v : 0.f;
      }
    }
  }
}

// ---------------- logits + top-2 + gates + margin-mark ----------------
__global__ __launch_bounds__(256) void k_logits_top2(const float* __restrict__ h_r,
                                                     const float* __restrict__ rw2,  // [RH][8]
                                                     const float* __restrict__ rb2,
                                                     int* __restrict__ sel, float* __restrict__ gate,
                                                     int* __restrict__ marked, int* __restrict__ mcount) {
  const int lane = threadIdx.x & 63, wid = threadIdx.x >> 6;
  const int n = blockIdx.x * 4 + wid;
  float p[8] = {0, 0, 0, 0, 0, 0, 0, 0};
  const float* hr = h_r + (long)n * RH_;
  for (int i = 0; i < RH_ / 64; i++) {
    int c = i * 64 + lane;
    float v = hr[c];
    float4 wa = ((const float4*)(rw2 + c * 8))[0];
    float4 wb = ((const float4*)(rw2 + c * 8))[1];
    p[0] += v * wa.x; p[1] += v * wa.y; p[2] += v * wa.z; p[3] += v * wa.w;
    p[4] += v * wb.x; p[5] += v * wb.y; p[6] += v * wb.z; p[7] += v * wb.w;
  }
  #pragma unroll
  for (int e = 0; e < 8; e++)
    #pragma unroll
    for (int s = 32; s >= 1; s >>= 1) p[e] += __shfl_xor(p[e], s, 64);
  if (lane == 0) {
    float l1 = -1e30f, l2 = -1e30f, l3 = -1e30f; int e1 = 0, e2 = 0;
    #pragma unroll
    for (int e = 0; e < 8; e++) {
      float v = p[e] + rb2[e];
      if (v > l1)      { l3 = l2; l2 = l1; e2 = e1; l1 = v; e1 = e; }
      else if (v > l2) { l3 = l2; l2 = v; e2 = e; }
      else if (v > l3) { l3 = v; }
    }
    float g1 = 1.f / (1.f + expf(l2 - l1));  // renormalized top-2 == pair softmax
    sel[n * 2] = e1; sel[n * 2 + 1] = e2;
    gate[n * 2] = g1; gate[n * 2 + 1] = 1.f - g1;
    if (l2 - l3 < DELTA_MARGIN) { int i = atomicAdd(mcount, 1); marked[i] = n; }
  }
}

// ---------------- fp64 fixup stage 1 ----------------
__global__ __launch_bounds__(256) void k_fixup1(const float* __restrict__ x,
                                                const float* __restrict__ ln_g, const float* __restrict__ ln_b,
                                                const float* __restrict__ rw1, const float* __restrict__ rb1,
                                                const int* __restrict__ marked, const int* __restrict__ mcount,
                                                double* __restrict__ hsbuf) {
  __shared__ float xs[D_];
  __shared__ float redf[4];
  __shared__ double part[64][5];
  const int tid = threadIdx.x;
  int cnt = *mcount; if (cnt > FIX_CAP) cnt = FIX_CAP;
  const int blkTok = blockIdx.x >> 5;   // 0..255
  const int chunk  = blockIdx.x & 31;   // 0..31
  for (int mi = blkTok; mi < cnt; mi += FIX_CAP) {
    const int n = marked[mi];
    float4 v = ((const float4*)(x + (long)n * D_))[tid];
    float s = v.x + v.y + v.z + v.w;
    #pragma unroll
    for (int o = 32; o >= 1; o >>= 1) s += __shfl_xor(s, o, 64);
    if ((tid & 63) == 0) redf[tid >> 6] = s;
    __syncthreads();
    float mean = (redf[0] + redf[1] + redf[2] + redf[3]) * (1.f / D_);
    __syncthreads();
    float d0 = v.x - mean, d1 = v.y - mean, d2 = v.z - mean, d3 = v.w - mean;
    float ss = d0 * d0 + d1 * d1 + d2 * d2 + d3 * d3;
    #pragma unroll
    for (int o = 32; o >= 1; o >>= 1) ss += __shfl_xor(ss, o, 64);
    if ((tid & 63) == 0) redf[tid >> 6] = ss;
    __syncthreads();
    float rstd = rsqrtf((redf[0] + redf[1] + redf[2] + redf[3]) * (1.f / D_) + 1e-5f);
    float4 gg = ((const float4*)ln_g)[tid];
    float4 bb = ((const float4*)ln_b)[tid];
    xs[tid * 4 + 0] = d0 * rstd * gg.x + bb.x;
    xs[tid * 4 + 1] = d1 * rstd * gg.y + bb.y;
    xs[tid * 4 + 2] = d2 * rstd * gg.z + bb.z;
    xs[tid * 4 + 3] = d3 * rstd * gg.w + bb.w;
    __syncthreads();
    const int lcol = tid & 63, prt = tid >> 6;
    const int col = chunk * 64 + lcol;
    const float* rp = rw1 + (long)(prt * 256) * RH_ + col;
    const float* xp = xs + prt * 256;
    double a0 = 0, a1 = 0, a2 = 0, a3 = 0;
    #pragma unroll 4
    for (int d = 0; d < 256; d += 4) {
      float w0 = rp[(long)(d + 0) * RH_];
      float w1 = rp[(long)(d + 1) * RH_];
      float w2 = rp[(long)(d + 2) * RH_];
      float w3 = rp[(long)(d + 3) * RH_];
      a0 += (double)xp[d + 0] * (double)w0;
      a1 += (double)xp[d + 1] * (double)w1;
      a2 += (double)xp[d + 2] * (double)w2;
      a3 += (double)xp[d + 3] * (double)w3;
    }
    part[lcol][prt] = (a0 + a1) + (a2 + a3);
    __syncthreads();
    if (tid < 64) {
      double a = (part[tid][0] + part[tid][1]) + (part[tid][2] + part[tid][3])
               + (double)rb1[chunk * 64 + tid];
      hsbuf[(long)mi * RH_ + chunk * 64 + tid] = a > 0.0 ? a : 0.0;
    }
    __syncthreads();
  }
}

// ---------------- fp64 fixup stage 2 ----------------
__global__ __launch_bounds__(256) void k_fixup2(const double* __restrict__ hsbuf,
                                                const float* __restrict__ rw2, const float* __restrict__ rb2,
                                                const int* __restrict__ marked, const int* __restrict__ mcount,
                                                int* __restrict__ sel, float* __restrict__ gate) {
  __shared__ double red2[256];
  const int tid = threadIdx.x;
  int cnt = *mcount; if (cnt > FIX_CAP) cnt = FIX_CAP;
  for (int mi = blockIdx.x; mi < cnt; mi += gridDim.x) {
    const int n = marked[mi];
    const double* hs = hsbuf + (long)mi * RH_;
    const int e = tid & 7, ch = tid >> 3;
    double pp = 0.0;
    for (int c = ch * 64; c < ch * 64 + 64; c++) pp += hs[c] * (double)rw2[c * 8 + e];
    red2[tid] = pp;
    __syncthreads();
    if (tid < 128) red2[tid] += red2[tid + 128];
    __syncthreads();
    if (tid < 64) red2[tid] += red2[tid + 64];
    __syncthreads();
    if (tid < 32) red2[tid] += red2[tid + 32];
    __syncthreads();
    if (tid < 16) red2[tid] += red2[tid + 16];
    __syncthreads();
    if (tid < 8) red2[tid] += red2[tid + 8];
    __syncthreads();
    if (tid == 0) {
      double l1 = -1e300, l2 = -1e300; int e1 = 0, e2 = 0;
      for (int ee = 0; ee < 8; ee++) {
        double vv = red2[ee] + (double)rb2[ee];
        if (vv > l1)      { l2 = l1; e2 = e1; l1 = vv; e1 = ee; }
        else if (vv > l2) { l2 = vv; e2 = ee; }
      }
      double g1 = 1.0 / (1.0 + exp(l2 - l1));
      sel[n * 2] = e1; sel[n * 2 + 1] = e2;
      gate[n * 2] = (float)g1; gate[n * 2 + 1] = (float)(1.0 - g1);
    }
    __syncthreads();
  }
}

// ---------------- dispatch build ----------------
__global__ void k_count(const int* __restrict__ sel, int* ctl) {
  int n = blockIdx.x * 256 + threadIdx.x;
  if (n >= N_) return;
  atomicAdd(&ctl[sel[n * 2]], 1);
  atomicAdd(&ctl[sel[n * 2 + 1]], 1);
}
__global__ void k_offsets(int* ctl) {
  if (threadIdx.x == 0 && blockIdx.x == 0) {
    int t = 0, tt = 0, t2 = 0;
    for (int e = 0; e < 8; e++) {
      ctl[8 + e] = t; ctl[17 + e] = tt; ctl[26 + e] = t; ctl[36 + e] = t2;
      t += ctl[e]; tt += (ctl[e] + 127) >> 7; t2 += (ctl[e] + 255) >> 8;
    }
    ctl[16] = t; ctl[25] = tt; ctl[44] = t2;
  }
}
__global__ void k_scatter(const int* __restrict__ sel, int* ctl,
                          int* __restrict__ perm, int* __restrict__ pos) {
  int n = blockIdx.x * 256 + threadIdx.x;
  if (n >= N_) return;
  #pragma unroll
  for (int k = 0; k < 2; k++) {
    int e = sel[n * 2 + k];
    int p = atomicAdd(&ctl[26 + e], 1);
    perm[p] = n;
    pos[n * 2 + k] = p;
  }
}

// ---------------- expert GEMMs: 256x256 tile, BK=64, 4-phase counted-vmcnt pipeline ----------------
// 8 waves (2M x 4N), per-wave 128x64 out. LDS 128 KB dbuf. Per K-tile: 4 phases, each
// {stage 1 half-tile of tile t+1 | 12 ds_read_b128 | setprio(1) 16 MFMA setprio(0) | s_barrier}.
// Tile-boundary: stage HT0(t+1) -> s_waitcnt vmcnt(2) (clears all 8 loads of tile t) -> barrier.
// vmcnt never 0 in-loop. Swizzle: PMC-verified slot' = slot ^ (row&7) (R7: 0 conflicts).
// KB = per-block K range (split-K via blockIdx.z). bias added only by z==0.
template <int KD, int KB, bool GATHER, bool RELU_BF16, bool MTFAST>
__global__ __launch_bounds__(512, 2) void k_gemm_expert8(const unsigned short* __restrict__ A,
                                                         const unsigned short* __restrict__ BT,
                                                         const float* __restrict__ bias,
                                                         const int* __restrict__ ctl,
                                                         const int* __restrict__ perm,
                                                         unsigned short* __restrict__ outBF,
                                                         float* __restrict__ outF32, int NB) {
  const int* cnt = ctl; const int* off = ctl + 8; const int* toff = ctl + 36;
  // ---- XCD-aware bijective block remap (x,y only; z = K-split) ----
  const int NX = gridDim.x, MT = gridDim.y;
  const int nwg = NX * MT;
  const int F = blockIdx.y * NX + blockIdx.x;
  const int q = nwg >> 3, r8 = nwg & 7;
  const int xcd = F & 7, j = F >> 3;
  const int L = (xcd < r8 ? xcd * (q + 1) : r8 * (q + 1) + (xcd - r8) * q) + j;
  int mt, nt;
  if (MTFAST) { mt = L % MT; nt = L / MT; }
  else        { nt = L % NX; mt = L / NX; }
  if (mt >= toff[8]) return;
  int e = 0;
  #pragma unroll
  for (int i = 0; i < 7; i++) if (toff[i + 1] <= mt) e = i + 1;
  const int ltile = mt - toff[e];
  const int g0 = off[e] + ltile * 256;
  int vrows = cnt[e] - ltile * 256; if (vrows > 256) vrows = 256;
  const int n0 = nt * 256;
  const long kbase = (long)blockIdx.z * KB;

  __shared__ __align__(16) unsigned short At[2][256 * 64];
  __shared__ __align__(16) unsigned short Bt[2][256 * 64];
  const int tid = threadIdx.x, lane = tid & 63, wid = tid >> 6;
  const int l8 = lane >> 3, s8 = lane & 7;
  const int ksw = (s8 ^ l8) * 8;          // pre-swizzled source k-slot (elems)

  // staging addresses: 4 A issues + 4 B issues, each issue = 64 rows (8/wave)
  long aA[4], aB[4];
  const long bbase = (long)e * NB * KD;
  const int gmax = off[e] + cnt[e] - 1;
  #pragma unroll
  for (int i = 0; i < 4; i++) {
    int row = i * 64 + wid * 8 + l8;
    long ar;
    if constexpr (GATHER) {
      int g = g0 + row;
      ar = perm[g <= gmax ? g : gmax];
    } else {
      ar = g0 + row;
    }
    aA[i] = ar * (long)KD + ksw + kbase;
    aB[i] = bbase + (long)(n0 + row) * KD + ksw + kbase;
  }

  const int wm = wid >> 2, wn = wid & 3;  // 2M x 4N wave grid
  const int rl = lane & 15, g4 = lane >> 4;
  int sl[2];
  #pragma unroll
  for (int ks = 0; ks < 2; ks++) sl[ks] = ((ks * 4 + g4) ^ (rl & 7)) * 8;

  f32x4 acc[8][4];
  #pragma unroll
  for (int i = 0; i < 8; i++)
    #pragma unroll
    for (int jj = 0; jj < 4; jj++) acc[i][jj] = 0.f;

  auto stage_ht = [&](int bi, int s, int k0) {  // s: 0,1=A halves; 2,3=B halves
    if (s < 2) {
      #pragma unroll
      for (int i = 0; i < 2; i++) {
        int is = s * 2 + i;
        GLOAD16(A + aA[is] + k0, &At[bi][(is * 64 + wid * 8) * 64]);
      }
    } else {
      #pragma unroll
      for (int i = 0; i < 2; i++) {
        int is = (s - 2) * 2 + i;
        GLOAD16(BT + aB[is] + k0, &Bt[bi][(is * 64 + wid * 8) * 64]);
      }
    }
  };

  constexpr int NT = KB / 64;
  // prologue: all 4 half-tiles of tile 0 into buf0 (8 loads/wave)
  #pragma unroll
  for (int s = 0; s < 4; s++) stage_ht(0, s, 0);

  int cur = 0;
  #pragma unroll 1
  for (int t = 0; t < NT; ++t) {
    const int k1 = (t + 1) * 64;
    #pragma unroll
    for (int p = 0; p < 4; ++p) {
      const int qm = p >> 1, qn = p & 1;
      if (p == 0) {
        if (t + 1 < NT) {
          stage_ht(cur ^ 1, 0, k1);
          asm volatile("s_waitcnt vmcnt(2)" ::: "memory");  // all 8 loads of tile t landed
        } else {
          asm volatile("s_waitcnt vmcnt(0)" ::: "memory");
        }
        __builtin_amdgcn_sched_barrier(0);
        __builtin_amdgcn_s_barrier();
        asm volatile("" ::: "memory");
      } else {
        if (t + 1 < NT) stage_ht(cur ^ 1, p, k1);
      }
      __builtin_amdgcn_s_setprio(1);
      bf16x8 bfr[2][2];
      #pragma unroll
      for (int ni = 0; ni < 2; ni++)
        #pragma unroll
        for (int ks = 0; ks < 2; ks++)
          bfr[ni][ks] = *(const bf16x8*)&Bt[cur][(wn * 64 + (qn * 2 + ni) * 16 + rl) * 64 + sl[ks]];
      #pragma unroll
      for (int mi = 0; mi < 4; mi++) {
        const int arow = (wm * 128 + (qm * 4 + mi) * 16 + rl) * 64;
        bf16x8 a0 = *(const bf16x8*)&At[cur][arow + sl[0]];
        bf16x8 a1 = *(const bf16x8*)&At[cur][arow + sl[1]];
        #pragma unroll
        for (int ni = 0; ni < 2; ni++) {
          acc[qm * 4 + mi][qn * 2 + ni] =
              __builtin_amdgcn_mfma_f32_16x16x32_bf16(a0, bfr[ni][0], acc[qm * 4 + mi][qn * 2 + ni], 0, 0, 0);
          acc[qm * 4 + mi][qn * 2 + ni] =
              __builtin_amdgcn_mfma_f32_16x16x32_bf16(a1, bfr[ni][1], acc[qm * 4 + mi][qn * 2 + ni], 0, 0, 0);
        }
      }
      __builtin_amdgcn_s_setprio(0);
      __builtin_amdgcn_s_barrier();
      asm volatile("" ::: "memory");
    }
    cur ^= 1;
  }

  // epilogue
  float* outZ = outF32 ? outF32 + (long)blockIdx.z * PSTRIDE : nullptr;
  const int rg4 = (lane >> 4) * 4;
  #pragma unroll
  for (int ni = 0; ni < 4; ni++) {
    int col = n0 + wn * 64 + ni * 16 + rl;
    float bv = (blockIdx.z == 0) ? bias[(long)e * NB + col] : 0.f;
    #pragma unroll
    for (int mi = 0; mi < 8; mi++) {
      int lrow = wm * 128 + mi * 16 + rg4;
      #pragma unroll
      for (int r = 0; r < 4; r++) {
        if (lrow + r < vrows) {
          float v = acc[mi][ni][r] + bv;
          long idx = (long)(g0 + lrow + r) * NB + col;
          if constexpr (RELU_BF16) outBF[idx] = f2bf(v > 0.f ? v : 0.f);
          else outZ[idx] = v;
        }
      }
    }
  }
}

// ---------------- combine: out = x + sum_k gate_k * (yp0[pos_k] + yp1[pos_k]) ----------------
__global__ __launch_bounds__(256) void k_combine(const float* __restrict__ x,
                                                 const float* __restrict__ y_part,
                                                 const int* __restrict__ pos,
                                                 const float* __restrict__ gate,
                                                 float* __restrict__ out) {
  const int n = blockIdx.x, t = threadIdx.x;
  const float g0 = gate[n * 2], g1 = gate[n * 2 + 1];
  const long p0 = pos[n * 2], p1 = pos[n * 2 + 1];
  float4 xv = ((const float4*)(x + (long)n * D_))[t];
  float4 a0 = ((const float4*)(y_part + p0 * D_))[t];
  float4 a1 = ((const float4*)(y_part + PSTRIDE + p0 * D_))[t];
  float4 b0 = ((const float4*)(y_part + p1 * D_))[t];
  float4 b1 = ((const float4*)(y_part + PSTRIDE + p1 * D_))[t];
  float4 o;
  o.x = xv.x + g0 * (a0.x + a1.x) + g1 * (b0.x + b1.x);
  o.y = xv.y + g0 * (a0.y + a1.y) + g1 * (b0.y + b1.y);
  o.z = xv.z + g0 * (a0.z + a1.z) + g1 * (b0.z + b1.z);
  o.w = xv.w + g0 * (a0.w + a1.w) + g1 * (b0.w + b1.w);
  ((float4*)(out + (long)n * D_))[t] = o;
}

extern "C" void kernel_launch(void* const* d_in, const int* in_sizes, int n_in,
                              void* d_out, int out_size, void* d_ws, size_t ws_size,
                              hipStream_t stream) {
  const float* x    = (const float*)d_in[0];
  const float* ln_g = (const float*)d_in[1];
  const float* ln_b = (const float*)d_in[2];
  const float* rw1  = (const float*)d_in[3];
  const float* rb1  = (const float*)d_in[4];
  const float* rw2  = (const float*)d_in[5];
  const float* rb2  = (const float*)d_in[6];
  const float* ew1  = (const float*)d_in[7];
  const float* eb1  = (const float*)d_in[8];
  const float* ew2  = (const float*)d_in[9];
  const float* eb2  = (const float*)d_in[10];
  float* out = (float*)d_out;

  char* w = (char*)d_ws;
  size_t off = 0;
  auto alloc = [&](size_t bytes) -> char* {
    char* p = w + off;
    off += (bytes + 255) & ~(size_t)255;
    return p;
  };
  unsigned short* ew1T  = (unsigned short*)alloc((size_t)E_ * H_ * D_ * 2);   // [E][H][D]
  unsigned short* ew2T  = (unsigned short*)alloc((size_t)E_ * D_ * H_ * 2);   // [E][D][H]
  unsigned short* rw1hT = (unsigned short*)alloc((size_t)RH_ * D_ * 2);       // [RH][D]
  unsigned short* rw1lT = (unsigned short*)alloc((size_t)RH_ * D_ * 2);
  unsigned short* xnh   = (unsigned short*)alloc((size_t)N_ * D_ * 2);
  unsigned short* xnl   = (unsigned short*)alloc((size_t)N_ * D_ * 2);
  float*          h_r   = (float*)alloc((size_t)N_ * RH_ * 4);
  unsigned short* h_buf = (unsigned short*)alloc((size_t)(NK_ + 256) * H_ * 2);
  float*          y_part = (float*)alloc((size_t)2 * PSTRIDE * 4);            // split-K partials
  double*         hsbuf = (double*)alloc((size_t)FIX_CAP * RH_ * 8);
  int*   sel    = (int*)alloc((size_t)N_ * 2 * 4);
  float* gate   = (float*)alloc((size_t)N_ * 2 * 4);
  int*   marked = (int*)alloc((size_t)N_ * 4);
  int*   perm   = (int*)alloc((size_t)NK_ * 4);
  int*   pos    = (int*)alloc((size_t)N_ * 2 * 4);
  int*   ctl    = (int*)alloc(64 * 4);

  // weight conversion (fp32 -> bf16, transposed to k-contiguous)
  k_transpose<<<dim3(H_ / 64, D_ / 64, E_), 256, 0, stream>>>(ew1, ew1T, nullptr, D_, H_);
  k_transpose<<<dim3(D_ / 64, H_ / 64, E_), 256, 0, stream>>>(ew2, ew2T, nullptr, H_, D_);
  k_transpose<<<dim3(RH_ / 64, D_ / 64, 1), 256, 0, stream>>>(rw1, rw1hT, rw1lT, D_, RH_);
  k_layernorm<<<N_, 256, 0, stream>>>(x, ln_g, ln_b, xnh, xnl);
  k_init<<<1, 64, 0, stream>>>(ctl);
  // router (bf16x2 ~ fp32-grade)
  k_router_gemm<<<dim3(N_ / 128, RH_ / 128), 256, 0, stream>>>(xnh, xnl, rw1hT, rw1lT, rb1, h_r);
  k_logits_top2<<<N_ / 4, 256, 0, stream>>>(h_r, rw2, rb2, sel, gate, marked, ctl + 34);
  // fp64 fixup for near-tie tokens
  k_fixup1<<<FIX_CAP * 32, 256, 0, stream>>>(x, ln_g, ln_b, rw1, rb1, marked, ctl + 34, hsbuf);
  k_fixup2<<<64, 256, 0, stream>>>(hsbuf, rw2, rb2, marked, ctl + 34, sel, gate);
  // dispatch
  k_count<<<N_ / 256, 256, 0, stream>>>(sel, ctl);
  k_offsets<<<1, 1, 0, stream>>>(ctl);
  k_scatter<<<N_ / 256, 256, 0, stream>>>(sel, ctl, perm, pos);
  // sparse expert FFN: 256x256 pipelined tiles; GEMM2 split-K=2
  k_gemm_expert8<D_, D_, true, true, true><<<dim3(H_ / 256, MT256_MAX, 1), 512, 0, stream>>>(
      xnh, ew1T, eb1, ctl, perm, h_buf, nullptr, H_);
  k_gemm_expert8<H_, H_ / 2, false, false, false><<<dim3(D_ / 256, MT256_MAX, 2), 512, 0, stream>>>(
      h_buf, ew2T, eb2, ctl, perm, nullptr, y_part, D_);
  k_combine<<<N_, 256, 0, stream>>>(x, y_part, pos, gate, out);

  (void)in_sizes; (void)n_in; (void)out_size; (void)ws_size;
}

// Round 10
// 587.356 us; speedup vs baseline: 1.1886x; 1.1886x over previous
//
#include <hip/hip_runtime.h>
#include <stdint.h>

#define D_    1024
#define H_    4096
#define RH_   2048
#define E_    8
#define N_    4096
#define NK_   8192          // N * TOP_K
#define MT_MAX 71           // worst-case sum of ceil(cnt_e/128)
#define MT256_MAX 39        // worst-case sum of ceil(cnt_e/256)
#define DELTA_MARGIN 1e-4f  // rank2-rank3 logit margin for fp64 fixup
#define FIX_CAP 256         // max tokens handled by fixup (cnt is ~O(1) in practice)
#define PSTRIDE ((long)(NK_ + 256) * D_)   // split-K partial slab stride (f32 elems)

typedef __bf16 bf16x8 __attribute__((ext_vector_type(8)));
typedef float  f32x4  __attribute__((ext_vector_type(4)));

// ctl layout (ints): [0..7]=cnt  [8..16]=off(prefix, off[8]=8192)
// [17..25]=tile_off128 [26..33]=cursor [34]=mcount [36..44]=tile_off256

__device__ __forceinline__ unsigned short f2bf(float f) {
  union { float f; unsigned u; } v; v.f = f;
  unsigned r = v.u + 0x7fffu + ((v.u >> 16) & 1u);  // RNE
  return (unsigned short)(r >> 16);
}
__device__ __forceinline__ float bf2f(unsigned short h) {
  union { unsigned u; float f; } v; v.u = ((unsigned)h) << 16;
  return v.f;
}

// async global->LDS, 16B per lane, LDS dest must be wave-uniform base (+lane*16 implicit)
#define GLOAD16(gp, lp) \
  __builtin_amdgcn_global_load_lds((__attribute__((address_space(1))) void*)(void*)(gp), \
                                   (__attribute__((address_space(3))) void*)(lp), 16, 0, 0)

// ---------------- transpose + fp32->bf16 (optionally hi/lo split) ----------------
__global__ __launch_bounds__(256) void k_transpose(const float* __restrict__ in,
                                                   unsigned short* __restrict__ outH,
                                                   unsigned short* __restrict__ outL,
                                                   int R, int C) {
  __shared__ float t[64][65];
  const int b = blockIdx.z;
  const int c0 = blockIdx.x * 64, r0 = blockIdx.y * 64;
  const int lx = threadIdx.x & 63, ly = threadIdx.x >> 6;   // ly in 0..3
  const long inB = (long)R * C;
  const float* ip = in + b * inB + (long)r0 * C + c0 + lx;
  #pragma unroll
  for (int i = 0; i < 16; i++)
    t[ly + i * 4][lx] = ip[(long)(ly + i * 4) * C];
  __syncthreads();
  const int wy = threadIdx.x >> 2;          // column 0..63
  const int wx = (threadIdx.x & 3) * 16;    // row-chunk offset
  const int c = c0 + wy;
  const long ob = b * inB + (long)c * R + r0 + wx;
  unsigned short h[16];
  #pragma unroll
  for (int j = 0; j < 16; j++) h[j] = f2bf(t[wx + j][wy]);
  #pragma unroll
  for (int j = 0; j < 4; j++)
    *(ushort4*)&outH[ob + j * 4] = make_ushort4(h[j*4], h[j*4+1], h[j*4+2], h[j*4+3]);
  if (outL) {
    unsigned short l[16];
    #pragma unroll
    for (int j = 0; j < 16; j++) l[j] = f2bf(t[wx + j][wy] - bf2f(h[j]));
    #pragma unroll
    for (int j = 0; j < 4; j++)
      *(ushort4*)&outL[ob + j * 4] = make_ushort4(l[j*4], l[j*4+1], l[j*4+2], l[j*4+3]);
  }
}

// ---------------- LayerNorm -> xn hi/lo bf16 ----------------
__global__ __launch_bounds__(256) void k_layernorm(const float* __restrict__ x,
                                                   const float* __restrict__ g,
                                                   const float* __restrict__ b,
                                                   unsigned short* __restrict__ xnh,
                                                   unsigned short* __restrict__ xnl) {
  __shared__ float red[4];
  const int n = blockIdx.x, tid = threadIdx.x;
  float4 v = ((const float4*)(x + (long)n * D_))[tid];
  float s = v.x + v.y + v.z + v.w;
  #pragma unroll
  for (int o = 32; o >= 1; o >>= 1) s += __shfl_xor(s, o, 64);
  if ((tid & 63) == 0) red[tid >> 6] = s;
  __syncthreads();
  float mean = (red[0] + red[1] + red[2] + red[3]) * (1.f / D_);
  __syncthreads();
  float d0 = v.x - mean, d1 = v.y - mean, d2 = v.z - mean, d3 = v.w - mean;
  float ss = d0 * d0 + d1 * d1 + d2 * d2 + d3 * d3;
  #pragma unroll
  for (int o = 32; o >= 1; o >>= 1) ss += __shfl_xor(ss, o, 64);
  if ((tid & 63) == 0) red[tid >> 6] = ss;
  __syncthreads();
  float rstd = rsqrtf((red[0] + red[1] + red[2] + red[3]) * (1.f / D_) + 1e-5f);
  float4 gg = ((const float4*)g)[tid];
  float4 bb = ((const float4*)b)[tid];
  float xn0 = d0 * rstd * gg.x + bb.x;
  float xn1 = d1 * rstd * gg.y + bb.y;
  float xn2 = d2 * rstd * gg.z + bb.z;
  float xn3 = d3 * rstd * gg.w + bb.w;
  unsigned short h0 = f2bf(xn0), h1 = f2bf(xn1), h2 = f2bf(xn2), h3 = f2bf(xn3);
  ((ushort4*)xnh)[(long)n * 256 + tid] = make_ushort4(h0, h1, h2, h3);
  ((ushort4*)xnl)[(long)n * 256 + tid] = make_ushort4(
      f2bf(xn0 - bf2f(h0)), f2bf(xn1 - bf2f(h1)),
      f2bf(xn2 - bf2f(h2)), f2bf(xn3 - bf2f(h3)));
}

__global__ void k_init(int* ctl) { if (threadIdx.x < 46) ctl[threadIdx.x] = 0; }

// ---------------- router GEMM: h_r = relu(xn @ rw1 + rb1), bf16x2 -> fp32-grade ----------------
__global__ __launch_bounds__(256) void k_router_gemm(const unsigned short* __restrict__ xh,
                                                     const unsigned short* __restrict__ xl,
                                                     const unsigned short* __restrict__ bhT,  // [RH][D]
                                                     const unsigned short* __restrict__ blT,
                                                     const float* __restrict__ rb1,
                                                     float* __restrict__ h_r) {
  __shared__ __align__(16) unsigned short Ah[128 * 32], Al[128 * 32], Bh[128 * 32], Bl[128 * 32];
  const int tid = threadIdx.x, lane = tid & 63, wid = tid >> 6;
  const int m0 = blockIdx.x * 128, n0 = blockIdx.y * 128;
  const int wm = wid >> 1, wn = wid & 1;
  const int seg0 = wid * 2;
  const int srow = lane >> 2;
  const int scol = (lane & 3) * 8;
  const long a0 = (long)(m0 + seg0 * 16 + srow) * D_ + scol;
  const long a1 = a0 + 16 * D_;
  const long b0 = (long)(n0 + seg0 * 16 + srow) * D_ + scol;
  const long b1 = b0 + 16 * D_;
  const int rl = lane & 15, kh8 = (lane >> 4) * 8;
  f32x4 acc[4][4];
  #pragma unroll
  for (int i = 0; i < 4; i++)
    #pragma unroll
    for (int j = 0; j < 4; j++) acc[i][j] = 0.f;

  for (int k0 = 0; k0 < D_; k0 += 32) {
    GLOAD16(xh + a0 + k0, Ah + seg0 * 512);
    GLOAD16(xh + a1 + k0, Ah + seg0 * 512 + 512);
    GLOAD16(xl + a0 + k0, Al + seg0 * 512);
    GLOAD16(xl + a1 + k0, Al + seg0 * 512 + 512);
    GLOAD16(bhT + b0 + k0, Bh + seg0 * 512);
    GLOAD16(bhT + b1 + k0, Bh + seg0 * 512 + 512);
    GLOAD16(blT + b0 + k0, Bl + seg0 * 512);
    GLOAD16(blT + b1 + k0, Bl + seg0 * 512 + 512);
    __syncthreads();
    bf16x8 bhf[4], blf[4];
    #pragma unroll
    for (int ni = 0; ni < 4; ni++) {
      int r = (wn * 64 + ni * 16 + rl) * 32 + kh8;
      bhf[ni] = *(const bf16x8*)(Bh + r);
      blf[ni] = *(const bf16x8*)(Bl + r);
    }
    #pragma unroll
    for (int mi = 0; mi < 4; mi++) {
      int r = (wm * 64 + mi * 16 + rl) * 32 + kh8;
      bf16x8 ah = *(const bf16x8*)(Ah + r);
      bf16x8 al = *(const bf16x8*)(Al + r);
      #pragma unroll
      for (int ni = 0; ni < 4; ni++) {
        acc[mi][ni] = __builtin_amdgcn_mfma_f32_16x16x32_bf16(ah, bhf[ni], acc[mi][ni], 0, 0, 0);
        acc[mi][ni] = __builtin_amdgcn_mfma_f32_16x16x32_bf16(ah, blf[ni], acc[mi][ni], 0, 0, 0);
        acc[mi][ni] = __builtin_amdgcn_mfma_f32_16x16x32_bf16(al, bhf[ni], acc[mi][ni], 0, 0, 0);
      }
    }
    __syncthreads();
  }
  const int rg4 = (lane >> 4) * 4;
  #pragma unroll
  for (int ni = 0; ni < 4; ni++) {
    int col = n0 + wn * 64 + ni * 16 + rl;
    float bias = rb1[col];
    #pragma unroll
    for (int mi = 0; mi < 4; mi++) {
      int row = m0 + wm * 64 + mi * 16 + rg4;
      #pragma unroll
      for (int r = 0; r < 4; r++) {
        float v = acc[mi][ni][r] + bias;
        h_r[(long)(row + r) * RH_ + col] = v > 0.f ? v : 0.f;
      }
    }
  }
}

// ---------------- logits + top-2 + gates + margin-mark ----------------
__global__ __launch_bounds__(256) void k_logits_top2(const float* __restrict__ h_r,
                                                     const float* __restrict__ rw2,  // [RH][8]
                                                     const float* __restrict__ rb2,
                                                     int* __restrict__ sel, float* __restrict__ gate,
                                                     int* __restrict__ marked, int* __restrict__ mcount) {
  const int lane = threadIdx.x & 63, wid = threadIdx.x >> 6;
  const int n = blockIdx.x * 4 + wid;
  float p[8] = {0, 0, 0, 0, 0, 0, 0, 0};
  const float* hr = h_r + (long)n * RH_;
  for (int i = 0; i < RH_ / 64; i++) {
    int c = i * 64 + lane;
    float v = hr[c];
    float4 wa = ((const float4*)(rw2 + c * 8))[0];
    float4 wb = ((const float4*)(rw2 + c * 8))[1];
    p[0] += v * wa.x; p[1] += v * wa.y; p[2] += v * wa.z; p[3] += v * wa.w;
    p[4] += v * wb.x; p[5] += v * wb.y; p[6] += v * wb.z; p[7] += v * wb.w;
  }
  #pragma unroll
  for (int e = 0; e < 8; e++)
    #pragma unroll
    for (int s = 32; s >= 1; s >>= 1) p[e] += __shfl_xor(p[e], s, 64);
  if (lane == 0) {
    float l1 = -1e30f, l2 = -1e30f, l3 = -1e30f; int e1 = 0, e2 = 0;
    #pragma unroll
    for (int e = 0; e < 8; e++) {
      float v = p[e] + rb2[e];
      if (v > l1)      { l3 = l2; l2 = l1; e2 = e1; l1 = v; e1 = e; }
      else if (v > l2) { l3 = l2; l2 = v; e2 = e; }
      else if (v > l3) { l3 = v; }
    }
    float g1 = 1.f / (1.f + expf(l2 - l1));  // renormalized top-2 == pair softmax
    sel[n * 2] = e1; sel[n * 2 + 1] = e2;
    gate[n * 2] = g1; gate[n * 2 + 1] = 1.f - g1;
    if (l2 - l3 < DELTA_MARGIN) { int i = atomicAdd(mcount, 1); marked[i] = n; }
  }
}

// ---------------- fp64 fixup stage 1 ----------------
__global__ __launch_bounds__(256) void k_fixup1(const float* __restrict__ x,
                                                const float* __restrict__ ln_g, const float* __restrict__ ln_b,
                                                const float* __restrict__ rw1, const float* __restrict__ rb1,
                                                const int* __restrict__ marked, const int* __restrict__ mcount,
                                                double* __restrict__ hsbuf) {
  __shared__ float xs[D_];
  __shared__ float redf[4];
  __shared__ double part[64][5];
  const int tid = threadIdx.x;
  int cnt = *mcount; if (cnt > FIX_CAP) cnt = FIX_CAP;
  const int blkTok = blockIdx.x >> 5;   // 0..255
  const int chunk  = blockIdx.x & 31;   // 0..31
  for (int mi = blkTok; mi < cnt; mi += FIX_CAP) {
    const int n = marked[mi];
    float4 v = ((const float4*)(x + (long)n * D_))[tid];
    float s = v.x + v.y + v.z + v.w;
    #pragma unroll
    for (int o = 32; o >= 1; o >>= 1) s += __shfl_xor(s, o, 64);
    if ((tid & 63) == 0) redf[tid >> 6] = s;
    __syncthreads();
    float mean = (redf[0] + redf[1] + redf[2] + redf[3]) * (1.f / D_);
    __syncthreads();
    float d0 = v.x - mean, d1 = v.y - mean, d2 = v.z - mean, d3 = v.w - mean;
    float ss = d0 * d0 + d1 * d1 + d2 * d2 + d3 * d3;
    #pragma unroll
    for (int o = 32; o >= 1; o >>= 1) ss += __shfl_xor(ss, o, 64);
    if ((tid & 63) == 0) redf[tid >> 6] = ss;
    __syncthreads();
    float rstd = rsqrtf((redf[0] + redf[1] + redf[2] + redf[3]) * (1.f / D_) + 1e-5f);
    float4 gg = ((const float4*)ln_g)[tid];
    float4 bb = ((const float4*)ln_b)[tid];
    xs[tid * 4 + 0] = d0 * rstd * gg.x + bb.x;
    xs[tid * 4 + 1] = d1 * rstd * gg.y + bb.y;
    xs[tid * 4 + 2] = d2 * rstd * gg.z + bb.z;
    xs[tid * 4 + 3] = d3 * rstd * gg.w + bb.w;
    __syncthreads();
    const int lcol = tid & 63, prt = tid >> 6;
    const int col = chunk * 64 + lcol;
    const float* rp = rw1 + (long)(prt * 256) * RH_ + col;
    const float* xp = xs + prt * 256;
    double a0 = 0, a1 = 0, a2 = 0, a3 = 0;
    #pragma unroll 4
    for (int d = 0; d < 256; d += 4) {
      float w0 = rp[(long)(d + 0) * RH_];
      float w1 = rp[(long)(d + 1) * RH_];
      float w2 = rp[(long)(d + 2) * RH_];
      float w3 = rp[(long)(d + 3) * RH_];
      a0 += (double)xp[d + 0] * (double)w0;
      a1 += (double)xp[d + 1] * (double)w1;
      a2 += (double)xp[d + 2] * (double)w2;
      a3 += (double)xp[d + 3] * (double)w3;
    }
    part[lcol][prt] = (a0 + a1) + (a2 + a3);
    __syncthreads();
    if (tid < 64) {
      double a = (part[tid][0] + part[tid][1]) + (part[tid][2] + part[tid][3])
               + (double)rb1[chunk * 64 + tid];
      hsbuf[(long)mi * RH_ + chunk * 64 + tid] = a > 0.0 ? a : 0.0;
    }
    __syncthreads();
  }
}

// ---------------- fp64 fixup stage 2 ----------------
__global__ __launch_bounds__(256) void k_fixup2(const double* __restrict__ hsbuf,
                                                const float* __restrict__ rw2, const float* __restrict__ rb2,
                                                const int* __restrict__ marked, const int* __restrict__ mcount,
                                                int* __restrict__ sel, float* __restrict__ gate) {
  __shared__ double red2[256];
  const int tid = threadIdx.x;
  int cnt = *mcount; if (cnt > FIX_CAP) cnt = FIX_CAP;
  for (int mi = blockIdx.x; mi < cnt; mi += gridDim.x) {
    const int n = marked[mi];
    const double* hs = hsbuf + (long)mi * RH_;
    const int e = tid & 7, ch = tid >> 3;
    double pp = 0.0;
    for (int c = ch * 64; c < ch * 64 + 64; c++) pp += hs[c] * (double)rw2[c * 8 + e];
    red2[tid] = pp;
    __syncthreads();
    if (tid < 128) red2[tid] += red2[tid + 128];
    __syncthreads();
    if (tid < 64) red2[tid] += red2[tid + 64];
    __syncthreads();
    if (tid < 32) red2[tid] += red2[tid + 32];
    __syncthreads();
    if (tid < 16) red2[tid] += red2[tid + 16];
    __syncthreads();
    if (tid < 8) red2[tid] += red2[tid + 8];
    __syncthreads();
    if (tid == 0) {
      double l1 = -1e300, l2 = -1e300; int e1 = 0, e2 = 0;
      for (int ee = 0; ee < 8; ee++) {
        double vv = red2[ee] + (double)rb2[ee];
        if (vv > l1)      { l2 = l1; e2 = e1; l1 = vv; e1 = ee; }
        else if (vv > l2) { l2 = vv; e2 = ee; }
      }
      double g1 = 1.0 / (1.0 + exp(l2 - l1));
      sel[n * 2] = e1; sel[n * 2 + 1] = e2;
      gate[n * 2] = (float)g1; gate[n * 2 + 1] = (float)(1.0 - g1);
    }
    __syncthreads();
  }
}

// ---------------- dispatch build ----------------
__global__ void k_count(const int* __restrict__ sel, int* ctl) {
  int n = blockIdx.x * 256 + threadIdx.x;
  if (n >= N_) return;
  atomicAdd(&ctl[sel[n * 2]], 1);
  atomicAdd(&ctl[sel[n * 2 + 1]], 1);
}
__global__ void k_offsets(int* ctl) {
  if (threadIdx.x == 0 && blockIdx.x == 0) {
    int t = 0, tt = 0, t2 = 0;
    for (int e = 0; e < 8; e++) {
      ctl[8 + e] = t; ctl[17 + e] = tt; ctl[26 + e] = t; ctl[36 + e] = t2;
      t += ctl[e]; tt += (ctl[e] + 127) >> 7; t2 += (ctl[e] + 255) >> 8;
    }
    ctl[16] = t; ctl[25] = tt; ctl[44] = t2;
  }
}
__global__ void k_scatter(const int* __restrict__ sel, int* ctl,
                          int* __restrict__ perm, int* __restrict__ pos) {
  int n = blockIdx.x * 256 + threadIdx.x;
  if (n >= N_) return;
  #pragma unroll
  for (int k = 0; k < 2; k++) {
    int e = sel[n * 2 + k];
    int p = atomicAdd(&ctl[26 + e], 1);
    perm[p] = n;
    pos[n * 2 + k] = p;
  }
}

// ---------------- expert GEMMs: 256x256 tile, BK=64, 2-phase-per-tile m201-order pipeline ----
// Phase = K=32 slice over the FULL per-wave out-tile (128x64): each fragment read once
// (8 A + 4 B ds_read_b128), 32 MFMA. m201 ordering: reads+stage issued BEFORE the opening
// barrier (latency absorbed in barrier wait, LDS drain overlaps other waves' MFMA);
// lgkmcnt(0)+sched_barrier after barrier (rule #18); vmcnt(0) only at tile seam, issued
// >= 1 full phase after the stage loads (~free). Swizzle PMC-verified (R7: 0 conflicts).
template <int KD, int KB, bool GATHER, bool RELU_BF16, bool MTFAST>
__global__ __launch_bounds__(512, 2) void k_gemm_expert9(const unsigned short* __restrict__ A,
                                                         const unsigned short* __restrict__ BT,
                                                         const float* __restrict__ bias,
                                                         const int* __restrict__ ctl,
                                                         const int* __restrict__ perm,
                                                         unsigned short* __restrict__ outBF,
                                                         float* __restrict__ outF32, int NB) {
  const int* cnt = ctl; const int* off = ctl + 8; const int* toff = ctl + 36;
  // ---- XCD-aware bijective block remap (x,y only; z = K-split) ----
  const int NX = gridDim.x, MT = gridDim.y;
  const int nwg = NX * MT;
  const int F = blockIdx.y * NX + blockIdx.x;
  const int q = nwg >> 3, r8 = nwg & 7;
  const int xcd = F & 7, j = F >> 3;
  const int L = (xcd < r8 ? xcd * (q + 1) : r8 * (q + 1) + (xcd - r8) * q) + j;
  int mt, nt;
  if (MTFAST) { mt = L % MT; nt = L / MT; }
  else        { nt = L % NX; mt = L / NX; }
  if (mt >= toff[8]) return;
  int e = 0;
  #pragma unroll
  for (int i = 0; i < 7; i++) if (toff[i + 1] <= mt) e = i + 1;
  const int ltile = mt - toff[e];
  const int g0 = off[e] + ltile * 256;
  int vrows = cnt[e] - ltile * 256; if (vrows > 256) vrows = 256;
  const int n0 = nt * 256;
  const long kbase = (long)blockIdx.z * KB;

  __shared__ __align__(16) unsigned short At[2][256 * 64];
  __shared__ __align__(16) unsigned short Bt[2][256 * 64];
  const int tid = threadIdx.x, lane = tid & 63, wid = tid >> 6;
  const int l8 = lane >> 3, s8 = lane & 7;
  const int ksw = (s8 ^ l8) * 8;          // pre-swizzled source k-slot (elems)

  long aA[4], aB[4];
  const long bbase = (long)e * NB * KD;
  const int gmax = off[e] + cnt[e] - 1;
  #pragma unroll
  for (int i = 0; i < 4; i++) {
    int row = i * 64 + wid * 8 + l8;
    long ar;
    if constexpr (GATHER) {
      int g = g0 + row;
      ar = perm[g <= gmax ? g : gmax];
    } else {
      ar = g0 + row;
    }
    aA[i] = ar * (long)KD + ksw + kbase;
    aB[i] = bbase + (long)(n0 + row) * KD + ksw + kbase;
  }

  const int wm = wid >> 2, wn = wid & 3;  // 2M x 4N wave grid; per-wave out 128x64
  const int rl = lane & 15, g4 = lane >> 4;
  int sl[2];
  #pragma unroll
  for (int ks = 0; ks < 2; ks++) sl[ks] = ((ks * 4 + g4) ^ (rl & 7)) * 8;

  f32x4 acc[8][4];
  #pragma unroll
  for (int i = 0; i < 8; i++)
    #pragma unroll
    for (int jj = 0; jj < 4; jj++) acc[i][jj] = 0.f;

  auto stageA = [&](int bi, int k0) {
    #pragma unroll
    for (int i = 0; i < 4; i++)
      GLOAD16(A + aA[i] + k0, &At[bi][(i * 64 + wid * 8) * 64]);
  };
  auto stageB = [&](int bi, int k0) {
    #pragma unroll
    for (int i = 0; i < 4; i++)
      GLOAD16(BT + aB[i] + k0, &Bt[bi][(i * 64 + wid * 8) * 64]);
  };

  constexpr int NT = KB / 64;
  stageA(0, 0); stageB(0, 0);
  asm volatile("s_waitcnt vmcnt(0)" ::: "memory");
  __builtin_amdgcn_sched_barrier(0);
  __builtin_amdgcn_s_barrier();

  int cur = 0;
  #pragma unroll 1
  for (int t = 0; t < NT; ++t) {
    const bool more = (t + 1 < NT);
    const int k1 = (t + 1) * 64;
    #pragma unroll
    for (int ks = 0; ks < 2; ++ks) {
      // --- reads for this phase (buf[cur] certified at tile seam) ---
      bf16x8 af[8], bf[4];
      #pragma unroll
      for (int mi = 0; mi < 8; mi++)
        af[mi] = *(const bf16x8*)&At[cur][(wm * 128 + mi * 16 + rl) * 64 + sl[ks]];
      #pragma unroll
      for (int ni = 0; ni < 4; ni++)
        bf[ni] = *(const bf16x8*)&Bt[cur][(wn * 64 + ni * 16 + rl) * 64 + sl[ks]];
      // --- stage next tile (all 8 loads at ks=0 -> >=1 phase of slack before vmcnt) ---
      if (ks == 0 && more) { stageA(cur ^ 1, k1); stageB(cur ^ 1, k1); }
      __builtin_amdgcn_sched_barrier(0);
      __builtin_amdgcn_s_barrier();
      asm volatile("s_waitcnt lgkmcnt(0)" ::: "memory");
      __builtin_amdgcn_sched_barrier(0);
      __builtin_amdgcn_s_setprio(1);
      #pragma unroll
      for (int ni = 0; ni < 4; ni++)
        #pragma unroll
        for (int mi = 0; mi < 8; mi++)
          acc[mi][ni] = __builtin_amdgcn_mfma_f32_16x16x32_bf16(af[mi], bf[ni], acc[mi][ni], 0, 0, 0);
      __builtin_amdgcn_s_setprio(0);
      if (ks == 1 && more) asm volatile("s_waitcnt vmcnt(0)" ::: "memory");  // tile seam
      __builtin_amdgcn_sched_barrier(0);
      __builtin_amdgcn_s_barrier();
    }
    cur ^= 1;
  }

  // epilogue
  float* outZ = outF32 ? outF32 + (long)blockIdx.z * PSTRIDE : nullptr;
  const int rg4 = (lane >> 4) * 4;
  #pragma unroll
  for (int ni = 0; ni < 4; ni++) {
    int col = n0 + wn * 64 + ni * 16 + rl;
    float bv = (blockIdx.z == 0) ? bias[(long)e * NB + col] : 0.f;
    #pragma unroll
    for (int mi = 0; mi < 8; mi++) {
      int lrow = wm * 128 + mi * 16 + rg4;
      #pragma unroll
      for (int r = 0; r < 4; r++) {
        if (lrow + r < vrows) {
          float v = acc[mi][ni][r] + bv;
          long idx = (long)(g0 + lrow + r) * NB + col;
          if constexpr (RELU_BF16) outBF[idx] = f2bf(v > 0.f ? v : 0.f);
          else outZ[idx] = v;
        }
      }
    }
  }
}

// ---------------- combine: out = x + sum_k gate_k * (yp0[pos_k] + yp1[pos_k]) ----------------
__global__ __launch_bounds__(256) void k_combine(const float* __restrict__ x,
                                                 const float* __restrict__ y_part,
                                                 const int* __restrict__ pos,
                                                 const float* __restrict__ gate,
                                                 float* __restrict__ out) {
  const int n = blockIdx.x, t = threadIdx.x;
  const float g0 = gate[n * 2], g1 = gate[n * 2 + 1];
  const long p0 = pos[n * 2], p1 = pos[n * 2 + 1];
  float4 xv = ((const float4*)(x + (long)n * D_))[t];
  float4 a0 = ((const float4*)(y_part + p0 * D_))[t];
  float4 a1 = ((const float4*)(y_part + PSTRIDE + p0 * D_))[t];
  float4 b0 = ((const float4*)(y_part + p1 * D_))[t];
  float4 b1 = ((const float4*)(y_part + PSTRIDE + p1 * D_))[t];
  float4 o;
  o.x = xv.x + g0 * (a0.x + a1.x) + g1 * (b0.x + b1.x);
  o.y = xv.y + g0 * (a0.y + a1.y) + g1 * (b0.y + b1.y);
  o.z = xv.z + g0 * (a0.z + a1.z) + g1 * (b0.z + b1.z);
  o.w = xv.w + g0 * (a0.w + a1.w) + g1 * (b0.w + b1.w);
  ((float4*)(out + (long)n * D_))[t] = o;
}

extern "C" void kernel_launch(void* const* d_in, const int* in_sizes, int n_in,
                              void* d_out, int out_size, void* d_ws, size_t ws_size,
                              hipStream_t stream) {
  const float* x    = (const float*)d_in[0];
  const float* ln_g = (const float*)d_in[1];
  const float* ln_b = (const float*)d_in[2];
  const float* rw1  = (const float*)d_in[3];
  const float* rb1  = (const float*)d_in[4];
  const float* rw2  = (const float*)d_in[5];
  const float* rb2  = (const float*)d_in[6];
  const float* ew1  = (const float*)d_in[7];
  const float* eb1  = (const float*)d_in[8];
  const float* ew2  = (const float*)d_in[9];
  const float* eb2  = (const float*)d_in[10];
  float* out = (float*)d_out;

  char* w = (char*)d_ws;
  size_t off = 0;
  auto alloc = [&](size_t bytes) -> char* {
    char* p = w + off;
    off += (bytes + 255) & ~(size_t)255;
    return p;
  };
  unsigned short* ew1T  = (unsigned short*)alloc((size_t)E_ * H_ * D_ * 2);   // [E][H][D]
  unsigned short* ew2T  = (unsigned short*)alloc((size_t)E_ * D_ * H_ * 2);   // [E][D][H]
  unsigned short* rw1hT = (unsigned short*)alloc((size_t)RH_ * D_ * 2);       // [RH][D]
  unsigned short* rw1lT = (unsigned short*)alloc((size_t)RH_ * D_ * 2);
  unsigned short* xnh   = (unsigned short*)alloc((size_t)N_ * D_ * 2);
  unsigned short* xnl   = (unsigned short*)alloc((size_t)N_ * D_ * 2);
  float*          h_r   = (float*)alloc((size_t)N_ * RH_ * 4);
  unsigned short* h_buf = (unsigned short*)alloc((size_t)(NK_ + 256) * H_ * 2);
  float*          y_part = (float*)alloc((size_t)2 * PSTRIDE * 4);            // split-K partials
  double*         hsbuf = (double*)alloc((size_t)FIX_CAP * RH_ * 8);
  int*   sel    = (int*)alloc((size_t)N_ * 2 * 4);
  float* gate   = (float*)alloc((size_t)N_ * 2 * 4);
  int*   marked = (int*)alloc((size_t)N_ * 4);
  int*   perm   = (int*)alloc((size_t)NK_ * 4);
  int*   pos    = (int*)alloc((size_t)N_ * 2 * 4);
  int*   ctl    = (int*)alloc(64 * 4);

  // weight conversion (fp32 -> bf16, transposed to k-contiguous)
  k_transpose<<<dim3(H_ / 64, D_ / 64, E_), 256, 0, stream>>>(ew1, ew1T, nullptr, D_, H_);
  k_transpose<<<dim3(D_ / 64, H_ / 64, E_), 256, 0, stream>>>(ew2, ew2T, nullptr, H_, D_);
  k_transpose<<<dim3(RH_ / 64, D_ / 64, 1), 256, 0, stream>>>(rw1, rw1hT, rw1lT, D_, RH_);
  k_layernorm<<<N_, 256, 0, stream>>>(x, ln_g, ln_b, xnh, xnl);
  k_init<<<1, 64, 0, stream>>>(ctl);
  // router (bf16x2 ~ fp32-grade)
  k_router_gemm<<<dim3(N_ / 128, RH_ / 128), 256, 0, stream>>>(xnh, xnl, rw1hT, rw1lT, rb1, h_r);
  k_logits_top2<<<N_ / 4, 256, 0, stream>>>(h_r, rw2, rb2, sel, gate, marked, ctl + 34);
  // fp64 fixup for near-tie tokens
  k_fixup1<<<FIX_CAP * 32, 256, 0, stream>>>(x, ln_g, ln_b, rw1, rb1, marked, ctl + 34, hsbuf);
  k_fixup2<<<64, 256, 0, stream>>>(hsbuf, rw2, rb2, marked, ctl + 34, sel, gate);
  // dispatch
  k_count<<<N_ / 256, 256, 0, stream>>>(sel, ctl);
  k_offsets<<<1, 1, 0, stream>>>(ctl);
  k_scatter<<<N_ / 256, 256, 0, stream>>>(sel, ctl, perm, pos);
  // sparse expert FFN: 256x256 pipelined tiles (m201-order phases); GEMM2 split-K=2
  k_gemm_expert9<D_, D_, true, true, true><<<dim3(H_ / 256, MT256_MAX, 1), 512, 0, stream>>>(
      xnh, ew1T, eb1, ctl, perm, h_buf, nullptr, H_);
  k_gemm_expert9<H_, H_ / 2, false, false, false><<<dim3(D_ / 256, MT256_MAX, 2), 512, 0, stream>>>(
      h_buf, ew2T, eb2, ctl, perm, nullptr, y_part, D_);
  k_combine<<<N_, 256, 0, stream>>>(x, y_part, pos, gate, out);

  (void)in_sizes; (void)n_in; (void)out_size; (void)ws_size;
}

// Round 11
// 525.076 us; speedup vs baseline: 1.3295x; 1.1186x over previous
//
#include <hip/hip_runtime.h>
#include <stdint.h>

#define D_    1024
#define H_    4096
#define RH_   2048
#define E_    8
#define N_    4096
#define NK_   8192          // N * TOP_K
#define MT_MAX 71           // worst-case sum of ceil(cnt_e/128)
#define DELTA_MARGIN 1e-4f  // rank2-rank3 logit margin for fp64 fixup
#define FIX_CAP 256         // max tokens handled by fixup (cnt is ~O(1) in practice)

typedef __bf16 bf16x8 __attribute__((ext_vector_type(8)));
typedef float  f32x4  __attribute__((ext_vector_type(4)));

// ctl layout (ints): [0..7]=cnt  [8..16]=off(prefix, off[8]=8192)
// [17..25]=tile_off128(prefix,[25]=total) [26..33]=cursor [34]=mcount

__device__ __forceinline__ unsigned short f2bf(float f) {
  union { float f; unsigned u; } v; v.f = f;
  unsigned r = v.u + 0x7fffu + ((v.u >> 16) & 1u);  // RNE
  return (unsigned short)(r >> 16);
}
__device__ __forceinline__ float bf2f(unsigned short h) {
  union { unsigned u; float f; } v; v.u = ((unsigned)h) << 16;
  return v.f;
}

// async global->LDS, 16B per lane, LDS dest must be wave-uniform base (+lane*16 implicit)
#define GLOAD16(gp, lp) \
  __builtin_amdgcn_global_load_lds((__attribute__((address_space(1))) void*)(void*)(gp), \
                                   (__attribute__((address_space(3))) void*)(lp), 16, 0, 0)

// ---------------- transpose + fp32->bf16 (optionally hi/lo split) ----------------
// 64x64 tiles; writes are 16 consecutive bf16 per thread -> 128B segments.
__global__ __launch_bounds__(256) void k_transpose(const float* __restrict__ in,
                                                   unsigned short* __restrict__ outH,
                                                   unsigned short* __restrict__ outL,
                                                   int R, int C) {
  __shared__ float t[64][65];
  const int b = blockIdx.z;
  const int c0 = blockIdx.x * 64, r0 = blockIdx.y * 64;
  const int lx = threadIdx.x & 63, ly = threadIdx.x >> 6;   // ly in 0..3
  const long inB = (long)R * C;
  const float* ip = in + b * inB + (long)r0 * C + c0 + lx;
  #pragma unroll
  for (int i = 0; i < 16; i++)
    t[ly + i * 4][lx] = ip[(long)(ly + i * 4) * C];
  __syncthreads();
  const int wy = threadIdx.x >> 2;          // column 0..63
  const int wx = (threadIdx.x & 3) * 16;    // row-chunk offset
  const int c = c0 + wy;
  const long ob = b * inB + (long)c * R + r0 + wx;
  unsigned short h[16];
  #pragma unroll
  for (int j = 0; j < 16; j++) h[j] = f2bf(t[wx + j][wy]);
  #pragma unroll
  for (int j = 0; j < 4; j++)
    *(ushort4*)&outH[ob + j * 4] = make_ushort4(h[j*4], h[j*4+1], h[j*4+2], h[j*4+3]);
  if (outL) {
    unsigned short l[16];
    #pragma unroll
    for (int j = 0; j < 16; j++) l[j] = f2bf(t[wx + j][wy] - bf2f(h[j]));
    #pragma unroll
    for (int j = 0; j < 4; j++)
      *(ushort4*)&outL[ob + j * 4] = make_ushort4(l[j*4], l[j*4+1], l[j*4+2], l[j*4+3]);
  }
}

// ---------------- LayerNorm -> xn hi/lo bf16 ----------------
__global__ __launch_bounds__(256) void k_layernorm(const float* __restrict__ x,
                                                   const float* __restrict__ g,
                                                   const float* __restrict__ b,
                                                   unsigned short* __restrict__ xnh,
                                                   unsigned short* __restrict__ xnl) {
  __shared__ float red[4];
  const int n = blockIdx.x, tid = threadIdx.x;
  float4 v = ((const float4*)(x + (long)n * D_))[tid];
  float s = v.x + v.y + v.z + v.w;
  #pragma unroll
  for (int o = 32; o >= 1; o >>= 1) s += __shfl_xor(s, o, 64);
  if ((tid & 63) == 0) red[tid >> 6] = s;
  __syncthreads();
  float mean = (red[0] + red[1] + red[2] + red[3]) * (1.f / D_);
  __syncthreads();
  float d0 = v.x - mean, d1 = v.y - mean, d2 = v.z - mean, d3 = v.w - mean;
  float ss = d0 * d0 + d1 * d1 + d2 * d2 + d3 * d3;
  #pragma unroll
  for (int o = 32; o >= 1; o >>= 1) ss += __shfl_xor(ss, o, 64);
  if ((tid & 63) == 0) red[tid >> 6] = ss;
  __syncthreads();
  float rstd = rsqrtf((red[0] + red[1] + red[2] + red[3]) * (1.f / D_) + 1e-5f);
  float4 gg = ((const float4*)g)[tid];
  float4 bb = ((const float4*)b)[tid];
  float xn0 = d0 * rstd * gg.x + bb.x;
  float xn1 = d1 * rstd * gg.y + bb.y;
  float xn2 = d2 * rstd * gg.z + bb.z;
  float xn3 = d3 * rstd * gg.w + bb.w;
  unsigned short h0 = f2bf(xn0), h1 = f2bf(xn1), h2 = f2bf(xn2), h3 = f2bf(xn3);
  ((ushort4*)xnh)[(long)n * 256 + tid] = make_ushort4(h0, h1, h2, h3);
  ((ushort4*)xnl)[(long)n * 256 + tid] = make_ushort4(
      f2bf(xn0 - bf2f(h0)), f2bf(xn1 - bf2f(h1)),
      f2bf(xn2 - bf2f(h2)), f2bf(xn3 - bf2f(h3)));
}

__global__ void k_init(int* ctl) { if (threadIdx.x < 36) ctl[threadIdx.x] = 0; }

// ---------------- router GEMM: h_r = relu(xn @ rw1 + rb1), bf16x2 -> fp32-grade ----------------
__global__ __launch_bounds__(256) void k_router_gemm(const unsigned short* __restrict__ xh,
                                                     const unsigned short* __restrict__ xl,
                                                     const unsigned short* __restrict__ bhT,  // [RH][D]
                                                     const unsigned short* __restrict__ blT,
                                                     const float* __restrict__ rb1,
                                                     float* __restrict__ h_r) {
  __shared__ __align__(16) unsigned short Ah[128 * 32], Al[128 * 32], Bh[128 * 32], Bl[128 * 32];
  const int tid = threadIdx.x, lane = tid & 63, wid = tid >> 6;
  const int m0 = blockIdx.x * 128, n0 = blockIdx.y * 128;
  const int wm = wid >> 1, wn = wid & 1;
  const int seg0 = wid * 2;
  const int srow = lane >> 2;
  const int scol = (lane & 3) * 8;
  const long a0 = (long)(m0 + seg0 * 16 + srow) * D_ + scol;
  const long a1 = a0 + 16 * D_;
  const long b0 = (long)(n0 + seg0 * 16 + srow) * D_ + scol;
  const long b1 = b0 + 16 * D_;
  const int rl = lane & 15, kh8 = (lane >> 4) * 8;
  f32x4 acc[4][4];
  #pragma unroll
  for (int i = 0; i < 4; i++)
    #pragma unroll
    for (int j = 0; j < 4; j++) acc[i][j] = 0.f;

  for (int k0 = 0; k0 < D_; k0 += 32) {
    GLOAD16(xh + a0 + k0, Ah + seg0 * 512);
    GLOAD16(xh + a1 + k0, Ah + seg0 * 512 + 512);
    GLOAD16(xl + a0 + k0, Al + seg0 * 512);
    GLOAD16(xl + a1 + k0, Al + seg0 * 512 + 512);
    GLOAD16(bhT + b0 + k0, Bh + seg0 * 512);
    GLOAD16(bhT + b1 + k0, Bh + seg0 * 512 + 512);
    GLOAD16(blT + b0 + k0, Bl + seg0 * 512);
    GLOAD16(blT + b1 + k0, Bl + seg0 * 512 + 512);
    __syncthreads();
    bf16x8 bhf[4], blf[4];
    #pragma unroll
    for (int ni = 0; ni < 4; ni++) {
      int r = (wn * 64 + ni * 16 + rl) * 32 + kh8;
      bhf[ni] = *(const bf16x8*)(Bh + r);
      blf[ni] = *(const bf16x8*)(Bl + r);
    }
    #pragma unroll
    for (int mi = 0; mi < 4; mi++) {
      int r = (wm * 64 + mi * 16 + rl) * 32 + kh8;
      bf16x8 ah = *(const bf16x8*)(Ah + r);
      bf16x8 al = *(const bf16x8*)(Al + r);
      #pragma unroll
      for (int ni = 0; ni < 4; ni++) {
        acc[mi][ni] = __builtin_amdgcn_mfma_f32_16x16x32_bf16(ah, bhf[ni], acc[mi][ni], 0, 0, 0);
        acc[mi][ni] = __builtin_amdgcn_mfma_f32_16x16x32_bf16(ah, blf[ni], acc[mi][ni], 0, 0, 0);
        acc[mi][ni] = __builtin_amdgcn_mfma_f32_16x16x32_bf16(al, bhf[ni], acc[mi][ni], 0, 0, 0);
      }
    }
    __syncthreads();
  }
  const int rg4 = (lane >> 4) * 4;
  #pragma unroll
  for (int ni = 0; ni < 4; ni++) {
    int col = n0 + wn * 64 + ni * 16 + rl;
    float bias = rb1[col];
    #pragma unroll
    for (int mi = 0; mi < 4; mi++) {
      int row = m0 + wm * 64 + mi * 16 + rg4;
      #pragma unroll
      for (int r = 0; r < 4; r++) {
        float v = acc[mi][ni][r] + bias;
        h_r[(long)(row + r) * RH_ + col] = v > 0.f ? v : 0.f;
      }
    }
  }
}

// ---------------- logits + top-2 + gates + margin-mark ----------------
__global__ __launch_bounds__(256) void k_logits_top2(const float* __restrict__ h_r,
                                                     const float* __restrict__ rw2,  // [RH][8]
                                                     const float* __restrict__ rb2,
                                                     int* __restrict__ sel, float* __restrict__ gate,
                                                     int* __restrict__ marked, int* __restrict__ mcount) {
  const int lane = threadIdx.x & 63, wid = threadIdx.x >> 6;
  const int n = blockIdx.x * 4 + wid;
  float p[8] = {0, 0, 0, 0, 0, 0, 0, 0};
  const float* hr = h_r + (long)n * RH_;
  for (int i = 0; i < RH_ / 64; i++) {
    int c = i * 64 + lane;
    float v = hr[c];
    float4 wa = ((const float4*)(rw2 + c * 8))[0];
    float4 wb = ((const float4*)(rw2 + c * 8))[1];
    p[0] += v * wa.x; p[1] += v * wa.y; p[2] += v * wa.z; p[3] += v * wa.w;
    p[4] += v * wb.x; p[5] += v * wb.y; p[6] += v * wb.z; p[7] += v * wb.w;
  }
  #pragma unroll
  for (int e = 0; e < 8; e++)
    #pragma unroll
    for (int s = 32; s >= 1; s >>= 1) p[e] += __shfl_xor(p[e], s, 64);
  if (lane == 0) {
    float l1 = -1e30f, l2 = -1e30f, l3 = -1e30f; int e1 = 0, e2 = 0;
    #pragma unroll
    for (int e = 0; e < 8; e++) {
      float v = p[e] + rb2[e];
      if (v > l1)      { l3 = l2; l2 = l1; e2 = e1; l1 = v; e1 = e; }
      else if (v > l2) { l3 = l2; l2 = v; e2 = e; }
      else if (v > l3) { l3 = v; }
    }
    float g1 = 1.f / (1.f + expf(l2 - l1));  // renormalized top-2 == pair softmax
    sel[n * 2] = e1; sel[n * 2 + 1] = e2;
    gate[n * 2] = g1; gate[n * 2 + 1] = 1.f - g1;
    if (l2 - l3 < DELTA_MARGIN) { int i = atomicAdd(mcount, 1); marked[i] = n; }
  }
}

// ---------------- fp64 fixup stage 1 ----------------
__global__ __launch_bounds__(256) void k_fixup1(const float* __restrict__ x,
                                                const float* __restrict__ ln_g, const float* __restrict__ ln_b,
                                                const float* __restrict__ rw1, const float* __restrict__ rb1,
                                                const int* __restrict__ marked, const int* __restrict__ mcount,
                                                double* __restrict__ hsbuf) {
  __shared__ float xs[D_];
  __shared__ float redf[4];
  __shared__ double part[64][5];
  const int tid = threadIdx.x;
  int cnt = *mcount; if (cnt > FIX_CAP) cnt = FIX_CAP;
  const int blkTok = blockIdx.x >> 5;   // 0..255
  const int chunk  = blockIdx.x & 31;   // 0..31
  for (int mi = blkTok; mi < cnt; mi += FIX_CAP) {
    const int n = marked[mi];
    float4 v = ((const float4*)(x + (long)n * D_))[tid];
    float s = v.x + v.y + v.z + v.w;
    #pragma unroll
    for (int o = 32; o >= 1; o >>= 1) s += __shfl_xor(s, o, 64);
    if ((tid & 63) == 0) redf[tid >> 6] = s;
    __syncthreads();
    float mean = (redf[0] + redf[1] + redf[2] + redf[3]) * (1.f / D_);
    __syncthreads();
    float d0 = v.x - mean, d1 = v.y - mean, d2 = v.z - mean, d3 = v.w - mean;
    float ss = d0 * d0 + d1 * d1 + d2 * d2 + d3 * d3;
    #pragma unroll
    for (int o = 32; o >= 1; o >>= 1) ss += __shfl_xor(ss, o, 64);
    if ((tid & 63) == 0) redf[tid >> 6] = ss;
    __syncthreads();
    float rstd = rsqrtf((redf[0] + redf[1] + redf[2] + redf[3]) * (1.f / D_) + 1e-5f);
    float4 gg = ((const float4*)ln_g)[tid];
    float4 bb = ((const float4*)ln_b)[tid];
    xs[tid * 4 + 0] = d0 * rstd * gg.x + bb.x;
    xs[tid * 4 + 1] = d1 * rstd * gg.y + bb.y;
    xs[tid * 4 + 2] = d2 * rstd * gg.z + bb.z;
    xs[tid * 4 + 3] = d3 * rstd * gg.w + bb.w;
    __syncthreads();
    const int lcol = tid & 63, prt = tid >> 6;
    const int col = chunk * 64 + lcol;
    const float* rp = rw1 + (long)(prt * 256) * RH_ + col;
    const float* xp = xs + prt * 256;
    double a0 = 0, a1 = 0, a2 = 0, a3 = 0;
    #pragma unroll 4
    for (int d = 0; d < 256; d += 4) {
      float w0 = rp[(long)(d + 0) * RH_];
      float w1 = rp[(long)(d + 1) * RH_];
      float w2 = rp[(long)(d + 2) * RH_];
      float w3 = rp[(long)(d + 3) * RH_];
      a0 += (double)xp[d + 0] * (double)w0;
      a1 += (double)xp[d + 1] * (double)w1;
      a2 += (double)xp[d + 2] * (double)w2;
      a3 += (double)xp[d + 3] * (double)w3;
    }
    part[lcol][prt] = (a0 + a1) + (a2 + a3);
    __syncthreads();
    if (tid < 64) {
      double a = (part[tid][0] + part[tid][1]) + (part[tid][2] + part[tid][3])
               + (double)rb1[chunk * 64 + tid];
      hsbuf[(long)mi * RH_ + chunk * 64 + tid] = a > 0.0 ? a : 0.0;
    }
    __syncthreads();
  }
}

// ---------------- fp64 fixup stage 2 ----------------
__global__ __launch_bounds__(256) void k_fixup2(const double* __restrict__ hsbuf,
                                                const float* __restrict__ rw2, const float* __restrict__ rb2,
                                                const int* __restrict__ marked, const int* __restrict__ mcount,
                                                int* __restrict__ sel, float* __restrict__ gate) {
  __shared__ double red2[256];
  const int tid = threadIdx.x;
  int cnt = *mcount; if (cnt > FIX_CAP) cnt = FIX_CAP;
  for (int mi = blockIdx.x; mi < cnt; mi += gridDim.x) {
    const int n = marked[mi];
    const double* hs = hsbuf + (long)mi * RH_;
    const int e = tid & 7, ch = tid >> 3;
    double pp = 0.0;
    for (int c = ch * 64; c < ch * 64 + 64; c++) pp += hs[c] * (double)rw2[c * 8 + e];
    red2[tid] = pp;
    __syncthreads();
    if (tid < 128) red2[tid] += red2[tid + 128];
    __syncthreads();
    if (tid < 64) red2[tid] += red2[tid + 64];
    __syncthreads();
    if (tid < 32) red2[tid] += red2[tid + 32];
    __syncthreads();
    if (tid < 16) red2[tid] += red2[tid + 16];
    __syncthreads();
    if (tid < 8) red2[tid] += red2[tid + 8];
    __syncthreads();
    if (tid == 0) {
      double l1 = -1e300, l2 = -1e300; int e1 = 0, e2 = 0;
      for (int ee = 0; ee < 8; ee++) {
        double vv = red2[ee] + (double)rb2[ee];
        if (vv > l1)      { l2 = l1; e2 = e1; l1 = vv; e1 = ee; }
        else if (vv > l2) { l2 = vv; e2 = ee; }
      }
      double g1 = 1.0 / (1.0 + exp(l2 - l1));
      sel[n * 2] = e1; sel[n * 2 + 1] = e2;
      gate[n * 2] = (float)g1; gate[n * 2 + 1] = (float)(1.0 - g1);
    }
    __syncthreads();
  }
}

// ---------------- dispatch build ----------------
__global__ void k_count(const int* __restrict__ sel, int* ctl) {
  int n = blockIdx.x * 256 + threadIdx.x;
  if (n >= N_) return;
  atomicAdd(&ctl[sel[n * 2]], 1);
  atomicAdd(&ctl[sel[n * 2 + 1]], 1);
}
__global__ void k_offsets(int* ctl) {
  if (threadIdx.x == 0 && blockIdx.x == 0) {
    int t = 0, tt = 0;
    for (int e = 0; e < 8; e++) {
      ctl[8 + e] = t; ctl[17 + e] = tt; ctl[26 + e] = t;
      t += ctl[e]; tt += (ctl[e] + 127) >> 7;
    }
    ctl[16] = t; ctl[25] = tt;
  }
}
__global__ void k_scatter(const int* __restrict__ sel, int* ctl,
                          int* __restrict__ perm, int* __restrict__ pos) {
  int n = blockIdx.x * 256 + threadIdx.x;
  if (n >= N_) return;
  #pragma unroll
  for (int k = 0; k < 2; k++) {
    int e = sel[n * 2 + k];
    int p = atomicAdd(&ctl[26 + e], 1);
    perm[p] = n;
    pos[n * 2 + k] = p;
  }
}

// ---------------- expert GEMMs (gathered), R6 structure + XCD-chunked remap ----------------
// 128x128 tile, BK=32, 4 waves, 16 KB LDS (proven ~3 blk/CU overlap, 141 us).
// Bijective XCD remap (m204). MTFAST: GEMM1 mt-fastest (B-panel L2-hot);
// GEMM2 nt-fastest (A-tile reused by its 8 N-blocks). Output always bf16; RELU optional.
template <int KD, bool GATHER, bool RELU, bool MTFAST>
__global__ __launch_bounds__(256) void k_gemm_expert(const unsigned short* __restrict__ A,
                                                     const unsigned short* __restrict__ BT,
                                                     const float* __restrict__ bias,
                                                     const int* __restrict__ ctl,
                                                     const int* __restrict__ perm,
                                                     unsigned short* __restrict__ outBF, int NB) {
  const int* cnt = ctl; const int* off = ctl + 8; const int* toff = ctl + 17;
  // ---- XCD-aware bijective block remap ----
  const int NX = gridDim.x, MT = gridDim.y;
  const int nwg = NX * MT;
  const int F = blockIdx.y * NX + blockIdx.x;
  const int q = nwg >> 3, r8 = nwg & 7;
  const int xcd = F & 7, j = F >> 3;
  const int L = (xcd < r8 ? xcd * (q + 1) : r8 * (q + 1) + (xcd - r8) * q) + j;
  int mt, nt;
  if (MTFAST) { mt = L % MT; nt = L / MT; }
  else        { nt = L % NX; mt = L / NX; }
  if (mt >= toff[8]) return;
  int e = 0;
  #pragma unroll
  for (int i = 0; i < 7; i++) if (toff[i + 1] <= mt) e = i + 1;
  const int ltile = mt - toff[e];
  const int g0 = off[e] + ltile * 128;
  int vrows = cnt[e] - ltile * 128; if (vrows > 128) vrows = 128;
  const int n0 = nt * 128;

  __shared__ __align__(16) unsigned short At[128 * 32], Bt[128 * 32];
  __shared__ int pidx[128];
  const int tid = threadIdx.x, lane = tid & 63, wid = tid >> 6;
  if constexpr (GATHER) {
    if (tid < 128) {
      int g = g0 + tid, gmax = off[e] + cnt[e] - 1;
      pidx[tid] = perm[g <= gmax ? g : gmax];
    }
    __syncthreads();
  }
  const int seg0 = wid * 2;
  const int srow0 = seg0 * 16 + (lane >> 2);
  const int scol = (lane & 3) * 8;
  long ab0, ab1;
  if constexpr (GATHER) {
    ab0 = (long)pidx[srow0] * KD + scol;
    ab1 = (long)pidx[srow0 + 16] * KD + scol;
  } else {
    ab0 = (long)(g0 + srow0) * KD + scol;
    ab1 = ab0 + (long)16 * KD;
  }
  const long bbase = (long)e * NB * KD;
  const long bb0 = bbase + (long)(n0 + srow0) * KD + scol;
  const long bb1 = bb0 + (long)16 * KD;

  const int wm = wid >> 1, wn = wid & 1;
  const int rl = lane & 15, kh8 = (lane >> 4) * 8;
  f32x4 acc[4][4];
  #pragma unroll
  for (int i = 0; i < 4; i++)
    #pragma unroll
    for (int jj = 0; jj < 4; jj++) acc[i][jj] = 0.f;

  for (int k0 = 0; k0 < KD; k0 += 32) {
    GLOAD16(A + ab0 + k0, At + seg0 * 512);
    GLOAD16(A + ab1 + k0, At + seg0 * 512 + 512);
    GLOAD16(BT + bb0 + k0, Bt + seg0 * 512);
    GLOAD16(BT + bb1 + k0, Bt + seg0 * 512 + 512);
    __syncthreads();
    bf16x8 bfr[4];
    #pragma unroll
    for (int ni = 0; ni < 4; ni++)
      bfr[ni] = *(const bf16x8*)(Bt + (wn * 64 + ni * 16 + rl) * 32 + kh8);
    #pragma unroll
    for (int mi = 0; mi < 4; mi++) {
      bf16x8 af = *(const bf16x8*)(At + (wm * 64 + mi * 16 + rl) * 32 + kh8);
      #pragma unroll
      for (int ni = 0; ni < 4; ni++)
        acc[mi][ni] = __builtin_amdgcn_mfma_f32_16x16x32_bf16(af, bfr[ni], acc[mi][ni], 0, 0, 0);
    }
    __syncthreads();
  }
  const int rg4 = (lane >> 4) * 4;
  #pragma unroll
  for (int ni = 0; ni < 4; ni++) {
    int col = n0 + wn * 64 + ni * 16 + rl;
    float bv = bias[(long)e * NB + col];
    #pragma unroll
    for (int mi = 0; mi < 4; mi++) {
      int lrow = wm * 64 + mi * 16 + rg4;
      #pragma unroll
      for (int r = 0; r < 4; r++) {
        if (lrow + r < vrows) {
          float v = acc[mi][ni][r] + bv;
          long idx = (long)(g0 + lrow + r) * NB + col;
          if constexpr (RELU) outBF[idx] = f2bf(v > 0.f ? v : 0.f);
          else                outBF[idx] = f2bf(v);
        }
      }
    }
  }
}

// ---------------- combine: out = x + g0*y[pos0] + g1*y[pos1] (y in bf16) ----------------
__global__ __launch_bounds__(256) void k_combine(const float* __restrict__ x,
                                                 const unsigned short* __restrict__ y_buf,
                                                 const int* __restrict__ pos,
                                                 const float* __restrict__ gate,
                                                 float* __restrict__ out) {
  const int n = blockIdx.x, t = threadIdx.x;
  const float g0 = gate[n * 2], g1 = gate[n * 2 + 1];
  const long p0 = pos[n * 2], p1 = pos[n * 2 + 1];
  float4 xv = ((const float4*)(x + (long)n * D_))[t];
  ushort4 ya = ((const ushort4*)(y_buf + p0 * D_))[t];
  ushort4 yb = ((const ushort4*)(y_buf + p1 * D_))[t];
  float4 o;
  o.x = xv.x + g0 * bf2f(ya.x) + g1 * bf2f(yb.x);
  o.y = xv.y + g0 * bf2f(ya.y) + g1 * bf2f(yb.y);
  o.z = xv.z + g0 * bf2f(ya.z) + g1 * bf2f(yb.z);
  o.w = xv.w + g0 * bf2f(ya.w) + g1 * bf2f(yb.w);
  ((float4*)(out + (long)n * D_))[t] = o;
}

extern "C" void kernel_launch(void* const* d_in, const int* in_sizes, int n_in,
                              void* d_out, int out_size, void* d_ws, size_t ws_size,
                              hipStream_t stream) {
  const float* x    = (const float*)d_in[0];
  const float* ln_g = (const float*)d_in[1];
  const float* ln_b = (const float*)d_in[2];
  const float* rw1  = (const float*)d_in[3];
  const float* rb1  = (const float*)d_in[4];
  const float* rw2  = (const float*)d_in[5];
  const float* rb2  = (const float*)d_in[6];
  const float* ew1  = (const float*)d_in[7];
  const float* eb1  = (const float*)d_in[8];
  const float* ew2  = (const float*)d_in[9];
  const float* eb2  = (const float*)d_in[10];
  float* out = (float*)d_out;

  char* w = (char*)d_ws;
  size_t off = 0;
  auto alloc = [&](size_t bytes) -> char* {
    char* p = w + off;
    off += (bytes + 255) & ~(size_t)255;
    return p;
  };
  unsigned short* ew1T  = (unsigned short*)alloc((size_t)E_ * H_ * D_ * 2);   // [E][H][D]
  unsigned short* ew2T  = (unsigned short*)alloc((size_t)E_ * D_ * H_ * 2);   // [E][D][H]
  unsigned short* rw1hT = (unsigned short*)alloc((size_t)RH_ * D_ * 2);       // [RH][D]
  unsigned short* rw1lT = (unsigned short*)alloc((size_t)RH_ * D_ * 2);
  unsigned short* xnh   = (unsigned short*)alloc((size_t)N_ * D_ * 2);
  unsigned short* xnl   = (unsigned short*)alloc((size_t)N_ * D_ * 2);
  float*          h_r   = (float*)alloc((size_t)N_ * RH_ * 4);
  unsigned short* h_buf = (unsigned short*)alloc((size_t)(NK_ + 128) * H_ * 2);
  unsigned short* y_buf = (unsigned short*)alloc((size_t)(NK_ + 128) * D_ * 2);
  double*         hsbuf = (double*)alloc((size_t)FIX_CAP * RH_ * 8);
  int*   sel    = (int*)alloc((size_t)N_ * 2 * 4);
  float* gate   = (float*)alloc((size_t)N_ * 2 * 4);
  int*   marked = (int*)alloc((size_t)N_ * 4);
  int*   perm   = (int*)alloc((size_t)NK_ * 4);
  int*   pos    = (int*)alloc((size_t)N_ * 2 * 4);
  int*   ctl    = (int*)alloc(64 * 4);

  // --- router path (rw1 transpose first; expert transposes deferred for LLC locality) ---
  k_transpose<<<dim3(RH_ / 64, D_ / 64, 1), 256, 0, stream>>>(rw1, rw1hT, rw1lT, D_, RH_);
  k_layernorm<<<N_, 256, 0, stream>>>(x, ln_g, ln_b, xnh, xnl);
  k_init<<<1, 64, 0, stream>>>(ctl);
  k_router_gemm<<<dim3(N_ / 128, RH_ / 128), 256, 0, stream>>>(xnh, xnl, rw1hT, rw1lT, rb1, h_r);
  k_logits_top2<<<N_ / 4, 256, 0, stream>>>(h_r, rw2, rb2, sel, gate, marked, ctl + 34);
  k_fixup1<<<FIX_CAP * 32, 256, 0, stream>>>(x, ln_g, ln_b, rw1, rb1, marked, ctl + 34, hsbuf);
  k_fixup2<<<64, 256, 0, stream>>>(hsbuf, rw2, rb2, marked, ctl + 34, sel, gate);
  // --- dispatch build ---
  k_count<<<N_ / 256, 256, 0, stream>>>(sel, ctl);
  k_offsets<<<1, 1, 0, stream>>>(ctl);
  k_scatter<<<N_ / 256, 256, 0, stream>>>(sel, ctl, perm, pos);
  // --- expert FFN: transpose each weight IMMEDIATELY before the GEMM that reads it,
  //     so the 64 MB bf16 panel is still LLC-resident (256 MB L3) when streamed. ---
  k_transpose<<<dim3(H_ / 64, D_ / 64, E_), 256, 0, stream>>>(ew1, ew1T, nullptr, D_, H_);
  k_gemm_expert<D_, true, true, true><<<dim3(H_ / 128, MT_MAX), 256, 0, stream>>>(
      xnh, ew1T, eb1, ctl, perm, h_buf, H_);
  k_transpose<<<dim3(D_ / 64, H_ / 64, E_), 256, 0, stream>>>(ew2, ew2T, nullptr, H_, D_);
  k_gemm_expert<H_, false, false, false><<<dim3(D_ / 128, MT_MAX), 256, 0, stream>>>(
      h_buf, ew2T, eb2, ctl, perm, y_buf, D_);
  k_combine<<<N_, 256, 0, stream>>>(x, y_buf, pos, gate, out);

  (void)in_sizes; (void)n_in; (void)out_size; (void)ws_size;
}